// Round 8
// baseline (177.531 us; speedup 1.0000x reference)
//
#include <hip/hip_runtime.h>
#include <math.h>

// Problem constants (match reference file)
#define NN   8192   // nodes
#define DF   64     // feature dim
#define KK   16     // k samples
#define MAXNBR 33   // self + up to 32 neighbors (row has <= 32 ones)
#define NT   512    // threads per block
#define NBINS 4096  // histogram bins = top 12 bits of flipped-float key
// transposed histogram layout: conflict-free 8-bin partial sums in stage 1
#define HIDX(b) ((((b) & 7) << 9) | ((b) >> 3))

__device__ __forceinline__ unsigned long long kmax(unsigned long long a, unsigned long long b) {
    return a > b ? a : b;
}
__device__ __forceinline__ unsigned long long kmin(unsigned long long a, unsigned long long b) {
    return a > b ? b : a;
}

// full 64-lane bitonic sort, descending (network validated in R7)
__device__ __forceinline__ void sort64_desc(unsigned long long& kv, int lane) {
    #pragma unroll
    for (int k = 2; k <= 64; k <<= 1) {
        #pragma unroll
        for (int j = k >> 1; j > 0; j >>= 1) {
            unsigned long long o = __shfl_xor(kv, j);
            bool tmax = (((lane & j) == 0) != ((lane & k) != 0));
            kv = tmax ? kmax(kv, o) : kmin(kv, o);
        }
    }
}

// ---- one block (8 waves) per node ----
__global__ __launch_bounds__(NT, 4)
void fused_kernel(const float* __restrict__ x,
                  const uint4* __restrict__ adj4,
                  const int*   __restrict__ cs,
                  int*         __restrict__ out)
{
    const int i    = blockIdx.x;           // node id
    const int t    = threadIdx.x;
    const int w    = t >> 6;
    const int lane = t & 63;

    __shared__ unsigned mask[NN / 32];                 // 1 KB dedup bitmap
    __shared__ int nbrs[MAXNBR];
    __shared__ int nnbr;
    __shared__ int nu_sh;
    __shared__ unsigned hist[NBINS];                   // 16 KB (transposed layout)
    __shared__ unsigned sum512[NT];                    // 2 KB stage-1 partial sums
    __shared__ unsigned long long surv[544];           // survivor keys
    __shared__ int nsurv;
    __shared__ int B_sh;

    // ---- phase A: init ----
    if (t < NN / 32) mask[t] = 0u;
    #pragma unroll
    for (int r = 0; r < NBINS / NT; ++r) hist[t + NT * r] = 0u;
    if (t == 0) { nbrs[0] = i; nnbr = 1; nu_sh = 0; nsurv = 0; }
    __syncthreads();                                   // barrier 1

    // ---- phase B: scan row i — 2048 uint4s, 4 per thread, all in flight ----
    const uint4* __restrict__ row4 = adj4 + (size_t)i * (NN / 4);
    uint4 v[4];
    #pragma unroll
    for (int u = 0; u < 4; ++u) v[u] = row4[t + NT * u];   // coalesced
    #pragma unroll
    for (int u = 0; u < 4; ++u) {
        if ((v[u].x | v[u].y | v[u].z | v[u].w) != 0u) {   // 1.0f == 0x3F800000
            const int base = 4 * (t + NT * u);
            const unsigned e[4] = {v[u].x, v[u].y, v[u].z, v[u].w};
            #pragma unroll
            for (int c2 = 0; c2 < 4; ++c2) {
                if (e[c2] != 0u) {
                    int s = atomicAdd(&nnbr, 1);
                    if (s < MAXNBR) nbrs[s] = base + c2;
                }
            }
        }
    }
    __syncthreads();                                   // barrier 2

    const int M = min(nnbr, MAXNBR);
    const int total = M * KK;                          // <= 528
    const float* __restrict__ xr = x + (size_t)i * DF; // block-uniform -> SGPRs

    // ---- phase C: gather candidates, dedup via shared bitmap ----
    // main: q = t; overflow q = 512..527 on wave-1 lanes 0..15
    int  v0 = 0, v1 = 0;
    bool ok0 = false, ok1 = false;
    if (t < total) {
        v0 = cs[(size_t)nbrs[t >> 4] * KK + (t & 15)];
        unsigned bit = 1u << (v0 & 31);
        unsigned old = atomicOr(&mask[v0 >> 5], bit);
        ok0 = !(old & bit);
    }
    const int q2 = NT + (t - 64);                      // 512..527 for t=64..79
    if (t >= 64 && t < 80 && q2 < total) {
        v1 = cs[(size_t)nbrs[q2 >> 4] * KK + (q2 & 15)];
        unsigned bit = 1u << (v1 & 31);
        unsigned old = atomicOr(&mask[v1 >> 5], bit);
        ok1 = !(old & bit);
    }

    // unique count: wave sum -> LDS add
    int myc = (ok0 ? 1 : 0) + (ok1 ? 1 : 0);
    #pragma unroll
    for (int off = 32; off; off >>= 1) myc += __shfl_xor(myc, off);
    if (lane == 0) atomicAdd(&nu_sh, myc);

    // ---- phase D: sims (strict sequential FMA chain d=0..63 — bit-exact) ----
    unsigned long long k0 = 0ULL, k1 = 0ULL;
    #pragma unroll
    for (int which = 0; which < 2; ++which) {
        const bool ok  = which ? ok1 : ok0;
        const int  val = which ? v1  : v0;
        if (ok) {
            const float4* xc4 = reinterpret_cast<const float4*>(x + (size_t)val * DF);
            float acc = 0.f;
            #pragma unroll
            for (int h = 0; h < 2; ++h) {
                float4 xv[8];
                #pragma unroll
                for (int d4 = 0; d4 < 8; ++d4) xv[d4] = xc4[8 * h + d4];
                #pragma unroll
                for (int d4 = 0; d4 < 8; ++d4) {
                    acc = fmaf(xr[32 * h + 4 * d4 + 0], xv[d4].x, acc);
                    acc = fmaf(xr[32 * h + 4 * d4 + 1], xv[d4].y, acc);
                    acc = fmaf(xr[32 * h + 4 * d4 + 2], xv[d4].z, acc);
                    acc = fmaf(xr[32 * h + 4 * d4 + 3], xv[d4].w, acc);
                }
            }
            unsigned fb = __float_as_uint(acc);
            fb = (fb & 0x80000000u) ? ~fb : (fb | 0x80000000u);   // order-preserving
            unsigned long long key = ((unsigned long long)fb << 13) |
                                     (unsigned long long)(unsigned)(8191 - val);
            if (which) k1 = key; else k0 = key;
        }
    }

    // ---- phase E: histogram of key top-12 bits ----
    if (ok0) atomicAdd(&hist[HIDX((unsigned)(k0 >> 33))], 1u);
    if (ok1) atomicAdd(&hist[HIDX((unsigned)(k1 >> 33))], 1u);
    __syncthreads();                                   // barrier 3 (hist + nu done)

    const int nu = nu_sh;

    if (nu >= KK) {
        // ---- phase F: find bin B containing the 16th-largest key ----
        // stage 1: 512 groups of 8 consecutive bins (transposed -> conflict-free)
        unsigned s8 = 0;
        #pragma unroll
        for (int j = 0; j < 8; ++j) s8 += hist[(j << 9) | t];   // bins 8t..8t+7
        sum512[t] = s8;
        __syncthreads();                               // barrier 4
        if (w == 0) {
            // stage 2: 64 chunks of 64 bins, scanned from top
            const int c = 63 - lane;                   // chunk id, descending
            unsigned c64 = 0;
            #pragma unroll
            for (int j = 0; j < 8; ++j) c64 += sum512[8 * c + j];
            unsigned p = c64;                          // inclusive prefix over lanes
            #pragma unroll
            for (int off = 1; off < 64; off <<= 1) {
                unsigned o = __shfl_up(p, off);
                if (lane >= off) p += o;
            }
            unsigned long long bal = __ballot(p >= (unsigned)KK);
            int l1 = (int)__ffsll((unsigned long long)bal) - 1;
            unsigned above1 = __shfl(p - c64, l1);     // count in chunks above C
            int C = 63 - l1;
            // stage 3: 64 bins of chunk C, descending
            int b = 64 * C + 63 - lane;
            unsigned hb = hist[HIDX(b)];
            unsigned p2 = hb;
            #pragma unroll
            for (int off = 1; off < 64; off <<= 1) {
                unsigned o = __shfl_up(p2, off);
                if (lane >= off) p2 += o;
            }
            unsigned long long bal2 = __ballot(above1 + p2 >= (unsigned)KK);
            int l2 = (int)__ffsll((unsigned long long)bal2) - 1;
            if (lane == 0) B_sh = 64 * C + 63 - l2;
        }
        __syncthreads();                               // barrier 5
        const unsigned Bv = (unsigned)B_sh;

        // ---- phase G: append survivors (bin >= B) ----
        if (ok0 && (unsigned)(k0 >> 33) >= Bv) { int s = atomicAdd(&nsurv, 1); surv[s] = k0; }
        if (ok1 && (unsigned)(k1 >> 33) >= Bv) { int s = atomicAdd(&nsurv, 1); surv[s] = k1; }
        __syncthreads();                               // barrier 6

        // ---- phase H: wave 0 sorts survivors exactly (u64 keys) ----
        if (w == 0) {
            const int S = nsurv;                       // >= 16 by construction
            unsigned long long kk = (lane < S) ? surv[lane] : 0ULL;
            sort64_desc(kk, lane);
            int processed = 64;
            while (processed < S) {                    // rare fallback: chunked resort
                if (lane >= 16) {
                    int idx = processed + (lane - 16);
                    kk = (idx < S) ? surv[idx] : 0ULL;
                }
                sort64_desc(kk, lane);
                processed += 48;
            }
            if (lane < KK)
                out[(size_t)i * KK + lane] = 8191 - (int)(kk & 0x1FFFULL);
        }
    } else {
        // rare: fewer than K uniques -> sorted uniques + pad with own samples
        if (t == 0) {
            int sorted_u[KK];
            int cnt2 = 0;
            for (int mw = 0; mw < NN / 32 && cnt2 < KK; ++mw) {
                unsigned b = mask[mw];
                while (b && cnt2 < KK) {
                    int bit = __ffs(b) - 1;
                    b &= b - 1;
                    sorted_u[cnt2++] = mw * 32 + bit;
                }
            }
            for (int j = 0; j < KK; ++j) {
                int vv;
                if (j < nu) {
                    vv = sorted_u[j];
                } else {
                    int idx = j - nu;
                    if (idx > KK - 1) idx = KK - 1;
                    vv = cs[(size_t)i * KK + idx];
                }
                out[(size_t)i * KK + j] = vv;
            }
        }
    }
}

extern "C" void kernel_launch(void* const* d_in, const int* in_sizes, int n_in,
                              void* d_out, int out_size, void* d_ws, size_t ws_size,
                              hipStream_t stream)
{
    const float* x   = (const float*)d_in[0];
    const float* adj = (const float*)d_in[1];
    const int*   cs  = (const int*)d_in[2];
    int* out = (int*)d_out;

    fused_kernel<<<NN, NT, 0, stream>>>(
        x, reinterpret_cast<const uint4*>(adj), cs, out);
}

// Round 10
// 156.988 us; speedup vs baseline: 1.1309x; 1.1309x over previous
//
#include <hip/hip_runtime.h>
#include <math.h>

// Problem constants (match reference file)
#define NN   8192   // nodes
#define DF   64     // feature dim
#define KK   16     // k samples
#define MAXNBR 33   // self + up to 32 neighbors (row has <= 32 ones)
#define NT   256    // threads per block (4 waves -> 8 blocks/CU possible)
#define NBINS 2048  // histogram bins = top 11 bits of flipped-float key
// transposed layout: thread t sums bins 8t..8t+7 conflict-free
#define HIDX(b) ((((b) & 7) << 8) | ((b) >> 3))

typedef unsigned uvec4 __attribute__((ext_vector_type(4)));  // NT-load-compatible

__device__ __forceinline__ unsigned long long kmax(unsigned long long a, unsigned long long b) {
    return a > b ? a : b;
}
__device__ __forceinline__ unsigned long long kmin(unsigned long long a, unsigned long long b) {
    return a > b ? b : a;
}

// full 64-lane bitonic sort, descending (validated R7/R8)
__device__ __forceinline__ void sort64_desc(unsigned long long& kv, int lane) {
    #pragma unroll
    for (int k = 2; k <= 64; k <<= 1) {
        #pragma unroll
        for (int j = k >> 1; j > 0; j >>= 1) {
            unsigned long long o = __shfl_xor(kv, j);
            bool tmax = (((lane & j) == 0) != ((lane & k) != 0));
            kv = tmax ? kmax(kv, o) : kmin(kv, o);
        }
    }
}

// ---- one block (4 waves) per node ----
__global__ __launch_bounds__(NT, 8)
void fused_kernel(const float* __restrict__ x,
                  const uvec4* __restrict__ adj4,
                  const int*   __restrict__ cs,
                  int*         __restrict__ out)
{
    const int i    = blockIdx.x;           // node id
    const int t    = threadIdx.x;
    const int w    = t >> 6;
    const int lane = t & 63;

    __shared__ unsigned mask[NN / 32];                 // 1 KB dedup bitmap
    __shared__ int nbrs[MAXNBR];
    __shared__ int nnbr;
    __shared__ int nu_sh;
    __shared__ unsigned hist[NBINS];                   // 8 KB (transposed layout)
    __shared__ unsigned sum256[NT];                    // 1 KB stage-1 partial sums
    __shared__ unsigned long long surv[544];           // survivor keys
    __shared__ int nsurv;
    __shared__ int B_sh;

    // ---- phase A: init ----
    if (t < NN / 32) mask[t] = 0u;                     // 256 words
    #pragma unroll
    for (int r = 0; r < NBINS / NT; ++r) hist[t + NT * r] = 0u;
    if (t == 0) { nbrs[0] = i; nnbr = 1; nu_sh = 0; nsurv = 0; }
    __syncthreads();                                   // barrier 1

    // ---- phase B: scan row i — 2048 uint4s, 8/thread, NON-TEMPORAL ----
    // adj is single-use streaming; NT hint keeps x + cs resident in L2.
    const uvec4* __restrict__ row4 = adj4 + (size_t)i * (NN / 4);
    uvec4 v[8];
    #pragma unroll
    for (int u = 0; u < 8; ++u) v[u] = __builtin_nontemporal_load(&row4[t + NT * u]);
    #pragma unroll
    for (int u = 0; u < 8; ++u) {
        if ((v[u].x | v[u].y | v[u].z | v[u].w) != 0u) {   // 1.0f == 0x3F800000
            const int base = 4 * (t + NT * u);
            const unsigned e[4] = {v[u].x, v[u].y, v[u].z, v[u].w};
            #pragma unroll
            for (int c2 = 0; c2 < 4; ++c2) {
                if (e[c2] != 0u) {
                    int s = atomicAdd(&nnbr, 1);
                    if (s < MAXNBR) nbrs[s] = base + c2;
                }
            }
        }
    }
    __syncthreads();                                   // barrier 2

    const int M = min(nnbr, MAXNBR);
    const int total = M * KK;                          // <= 528
    const float* __restrict__ xr = x + (size_t)i * DF; // block-uniform -> SGPRs

    // ---- phase C: gather candidates, dedup via shared bitmap ----
    // q = t, q = t+256, overflow q = 512..527 on wave-1 lanes 0..15
    int  vv[3] = {0, 0, 0};
    bool ok[3] = {false, false, false};
    #pragma unroll
    for (int r = 0; r < 2; ++r) {
        int q = t + NT * r;
        if (q < total) {
            vv[r] = cs[(size_t)nbrs[q >> 4] * KK + (q & 15)];
            unsigned bit = 1u << (vv[r] & 31);
            unsigned old = atomicOr(&mask[vv[r] >> 5], bit);
            ok[r] = !(old & bit);
        }
    }
    const int q2 = 2 * NT + (t - 64);                  // 512..527 for t=64..79
    if (t >= 64 && t < 80 && q2 < total) {
        vv[2] = cs[(size_t)nbrs[q2 >> 4] * KK + (q2 & 15)];
        unsigned bit = 1u << (vv[2] & 31);
        unsigned old = atomicOr(&mask[vv[2] >> 5], bit);
        ok[2] = !(old & bit);
    }

    // unique count: wave sum -> LDS add
    int myc = (ok[0] ? 1 : 0) + (ok[1] ? 1 : 0) + (ok[2] ? 1 : 0);
    #pragma unroll
    for (int off = 32; off; off >>= 1) myc += __shfl_xor(myc, off);
    if (lane == 0) atomicAdd(&nu_sh, myc);

    // ---- phase D: sims (strict sequential FMA chain d=0..63 — bit-exact) ----
    unsigned long long keys[3] = {0ULL, 0ULL, 0ULL};
    #pragma unroll
    for (int which = 0; which < 3; ++which) {
        if (ok[which]) {
            const float4* xc4 = reinterpret_cast<const float4*>(x + (size_t)vv[which] * DF);
            float acc = 0.f;
            #pragma unroll
            for (int h = 0; h < 2; ++h) {
                float4 xv[8];
                #pragma unroll
                for (int d4 = 0; d4 < 8; ++d4) xv[d4] = xc4[8 * h + d4];
                #pragma unroll
                for (int d4 = 0; d4 < 8; ++d4) {
                    acc = fmaf(xr[32 * h + 4 * d4 + 0], xv[d4].x, acc);
                    acc = fmaf(xr[32 * h + 4 * d4 + 1], xv[d4].y, acc);
                    acc = fmaf(xr[32 * h + 4 * d4 + 2], xv[d4].z, acc);
                    acc = fmaf(xr[32 * h + 4 * d4 + 3], xv[d4].w, acc);
                }
            }
            unsigned fb = __float_as_uint(acc);
            fb = (fb & 0x80000000u) ? ~fb : (fb | 0x80000000u);   // order-preserving
            keys[which] = ((unsigned long long)fb << 13) |
                          (unsigned long long)(unsigned)(8191 - vv[which]);
        }
    }

    // ---- phase E: histogram of key top-11 bits ----
    #pragma unroll
    for (int which = 0; which < 3; ++which)
        if (ok[which]) atomicAdd(&hist[HIDX((unsigned)(keys[which] >> 34))], 1u);
    __syncthreads();                                   // barrier 3 (hist + nu done)

    const int nu = nu_sh;

    if (nu >= KK) {
        // ---- phase F: find bin B containing the 16th-largest key ----
        // stage 1: thread t sums bins 8t..8t+7 (transposed -> conflict-free)
        unsigned s8 = 0;
        #pragma unroll
        for (int j = 0; j < 8; ++j) s8 += hist[(j << 8) | t];
        sum256[t] = s8;
        __syncthreads();                               // barrier 4
        if (w == 0) {
            // stage 2: 64 chunks of 32 bins, scanned from top
            const int c = 63 - lane;                   // chunk id, descending
            unsigned c32 = 0;
            #pragma unroll
            for (int j = 0; j < 4; ++j) c32 += sum256[4 * c + j];
            unsigned p = c32;                          // inclusive prefix (desc bins)
            #pragma unroll
            for (int off = 1; off < 64; off <<= 1) {
                unsigned o = __shfl_up(p, off);
                if (lane >= off) p += o;
            }
            unsigned long long bal = __ballot(p >= (unsigned)KK);
            int l1 = (int)__ffsll((unsigned long long)bal) - 1;
            unsigned above1 = __shfl(p - c32, l1);     // count in chunks above C
            int C = 63 - l1;
            // stage 3: 32 bins of chunk C, descending (lanes 0..31; others 0)
            int b = 32 * C + 31 - lane;
            unsigned hb = (lane < 32) ? hist[HIDX(b)] : 0u;
            unsigned p2 = hb;
            #pragma unroll
            for (int off = 1; off < 64; off <<= 1) {
                unsigned o = __shfl_up(p2, off);
                if (lane >= off) p2 += o;
            }
            unsigned long long bal2 = __ballot(above1 + p2 >= (unsigned)KK);
            int l2 = (int)__ffsll((unsigned long long)bal2) - 1;
            if (lane == 0) B_sh = 32 * C + 31 - l2;
        }
        __syncthreads();                               // barrier 5
        const unsigned Bv = (unsigned)B_sh;

        // ---- phase G: append survivors (bin >= B) ----
        #pragma unroll
        for (int which = 0; which < 3; ++which)
            if (ok[which] && (unsigned)(keys[which] >> 34) >= Bv) {
                int s = atomicAdd(&nsurv, 1);
                surv[s] = keys[which];
            }
        __syncthreads();                               // barrier 6

        // ---- phase H: wave 0 sorts survivors exactly (u64 keys) ----
        if (w == 0) {
            const int S = nsurv;                       // >= 16 by construction
            unsigned long long kk = (lane < S) ? surv[lane] : 0ULL;
            sort64_desc(kk, lane);
            int processed = 64;
            while (processed < S) {                    // rare fallback: chunked resort
                if (lane >= 16) {
                    int idx = processed + (lane - 16);
                    kk = (idx < S) ? surv[idx] : 0ULL;
                }
                sort64_desc(kk, lane);
                processed += 48;
            }
            if (lane < KK)
                out[(size_t)i * KK + lane] = 8191 - (int)(kk & 0x1FFFULL);
        }
    } else {
        // rare: fewer than K uniques -> sorted uniques + pad with own samples
        if (t == 0) {
            int sorted_u[KK];
            int cnt2 = 0;
            for (int mw = 0; mw < NN / 32 && cnt2 < KK; ++mw) {
                unsigned b = mask[mw];
                while (b && cnt2 < KK) {
                    int bit = __ffs(b) - 1;
                    b &= b - 1;
                    sorted_u[cnt2++] = mw * 32 + bit;
                }
            }
            for (int j = 0; j < KK; ++j) {
                int uu;
                if (j < nu) {
                    uu = sorted_u[j];
                } else {
                    int idx = j - nu;
                    if (idx > KK - 1) idx = KK - 1;
                    uu = cs[(size_t)i * KK + idx];
                }
                out[(size_t)i * KK + j] = uu;
            }
        }
    }
}

extern "C" void kernel_launch(void* const* d_in, const int* in_sizes, int n_in,
                              void* d_out, int out_size, void* d_ws, size_t ws_size,
                              hipStream_t stream)
{
    const float* x   = (const float*)d_in[0];
    const float* adj = (const float*)d_in[1];
    const int*   cs  = (const int*)d_in[2];
    int* out = (int*)d_out;

    fused_kernel<<<NN, NT, 0, stream>>>(
        x, reinterpret_cast<const uvec4*>(adj), cs, out);
}

// Round 11
// 115.796 us; speedup vs baseline: 1.5331x; 1.3557x over previous
//
#include <hip/hip_runtime.h>
#include <math.h>

// Problem constants (match reference file)
#define NN   8192   // nodes
#define DF   64     // feature dim
#define KK   16     // k samples
#define MAXNBR 33   // self + up to 32 neighbors (row has <= 32 ones)
#define NT   256    // threads per block (4 waves)
#define NBINS 2048  // histogram bins = top 11 bits of flipped-float key
#define MAXC 544
// transposed layout: thread t sums bins 8t..8t+7 conflict-free
#define HIDX(b) ((((b) & 7) << 8) | ((b) >> 3))

typedef unsigned uvec4 __attribute__((ext_vector_type(4)));  // NT-load-compatible

__device__ __forceinline__ unsigned long long kmax(unsigned long long a, unsigned long long b) {
    return a > b ? a : b;
}
__device__ __forceinline__ unsigned long long kmin(unsigned long long a, unsigned long long b) {
    return a > b ? b : a;
}

// full 64-lane bitonic sort, descending (validated R7/R8/R10)
__device__ __forceinline__ void sort64_desc(unsigned long long& kv, int lane) {
    #pragma unroll
    for (int k = 2; k <= 64; k <<= 1) {
        #pragma unroll
        for (int j = k >> 1; j > 0; j >>= 1) {
            unsigned long long o = __shfl_xor(kv, j);
            bool tmax = (((lane & j) == 0) != ((lane & k) != 0));
            kv = tmax ? kmax(kv, o) : kmin(kv, o);
        }
    }
}

// ---- one block (4 waves) per node ----
__global__ __launch_bounds__(NT, 8)
void fused_kernel(const float* __restrict__ x,
                  const uvec4* __restrict__ adj4,
                  const int*   __restrict__ cs,
                  int*         __restrict__ out)
{
    const int i    = blockIdx.x;           // node id
    const int t    = threadIdx.x;
    const int w    = t >> 6;
    const int lane = t & 63;

    __shared__ unsigned mask[NN / 32];                  // 1 KB dedup bitmap
    __shared__ int nbrs[MAXNBR];
    __shared__ int nnbr;
    __shared__ int cand[MAXC];                          // unique candidate values
    __shared__ int ncand;
    __shared__ unsigned long long skeys[MAXC];          // per-candidate keys
    __shared__ unsigned long long histsurv[NBINS / 2];  // 8 KB: hist (u32x2048) then surv (u64x544)
    __shared__ unsigned sum256[NT];                     // stage-1 partial sums
    __shared__ int nsurv;
    __shared__ int B_sh;
    unsigned* const hist = reinterpret_cast<unsigned*>(histsurv);
    unsigned long long* const surv = histsurv;

    // ---- phase A: init ----
    if (t < NN / 32) mask[t] = 0u;                      // 256 words
    #pragma unroll
    for (int r = 0; r < 4; ++r) histsurv[t + NT * r] = 0ULL;  // clears 2048 u32 bins
    if (t == 0) { nbrs[0] = i; nnbr = 1; ncand = 0; nsurv = 0; }
    __syncthreads();                                    // barrier 1

    // ---- phase B: scan row i — 2048 uint4s, 8/thread, NON-TEMPORAL ----
    const uvec4* __restrict__ row4 = adj4 + (size_t)i * (NN / 4);
    uvec4 v[8];
    #pragma unroll
    for (int u = 0; u < 8; ++u) v[u] = __builtin_nontemporal_load(&row4[t + NT * u]);
    #pragma unroll
    for (int u = 0; u < 8; ++u) {
        if ((v[u].x | v[u].y | v[u].z | v[u].w) != 0u) {    // 1.0f == 0x3F800000
            const int base = 4 * (t + NT * u);
            const unsigned e[4] = {v[u].x, v[u].y, v[u].z, v[u].w};
            #pragma unroll
            for (int c2 = 0; c2 < 4; ++c2) {
                if (e[c2] != 0u) {
                    int s = atomicAdd(&nnbr, 1);
                    if (s < MAXNBR) nbrs[s] = base + c2;
                }
            }
        }
    }
    __syncthreads();                                    // barrier 2

    const int M = min(nnbr, MAXNBR);
    const int total = M * KK;                           // <= 528

    // ---- phase C: gather cs, dedup via bitmap, append uniques to cand list ----
    #pragma unroll
    for (int r = 0; r < 2; ++r) {
        int q = t + NT * r;
        if (q < total) {
            int vv = cs[(size_t)nbrs[q >> 4] * KK + (q & 15)];
            unsigned bit = 1u << (vv & 31);
            unsigned old = atomicOr(&mask[vv >> 5], bit);
            if (!(old & bit)) { int s = atomicAdd(&ncand, 1); cand[s] = vv; }
        }
    }
    const int q2 = 2 * NT + (t - 64);                   // 512..527 for t=64..79
    if (t >= 64 && t < 80 && q2 < total) {
        int vv = cs[(size_t)nbrs[q2 >> 4] * KK + (q2 & 15)];
        unsigned bit = 1u << (vv & 31);
        unsigned old = atomicOr(&mask[vv >> 5], bit);
        if (!(old & bit)) { int s = atomicAdd(&ncand, 1); cand[s] = vv; }
    }
    __syncthreads();                                    // barrier 3

    const int ncv = ncand;                              // unique count

    // ---- phase D: sims — 16-lane cooperative, coalesced 256B row reads ----
    // group g (16 lanes) handles candidates g, g+16, ... : lanes load 16
    // consecutive float4s (2x128B transactions vs 64x16B scattered).
    const int g  = t >> 4;                              // 16 groups
    const int gl = t & 15;                              // lane in group
    const float4 xi4 = reinterpret_cast<const float4*>(x + (size_t)i * DF)[gl];
    #pragma unroll 4
    for (int c = g; c < ncv; c += 16) {
        const int val = cand[c];
        const float4 xv = reinterpret_cast<const float4*>(x + (size_t)val * DF)[gl];
        float acc = 0.f;
        acc = fmaf(xi4.x, xv.x, acc);
        acc = fmaf(xi4.y, xv.y, acc);
        acc = fmaf(xi4.z, xv.z, acc);
        acc = fmaf(xi4.w, xv.w, acc);
        // tree-reduce across the 16-lane group (xor offsets stay in-group)
        acc += __shfl_xor(acc, 8);
        acc += __shfl_xor(acc, 4);
        acc += __shfl_xor(acc, 2);
        acc += __shfl_xor(acc, 1);
        if (gl == 0) {
            unsigned fb = __float_as_uint(acc);
            fb = (fb & 0x80000000u) ? ~fb : (fb | 0x80000000u);   // order-preserving
            unsigned long long key = ((unsigned long long)fb << 13) |
                                     (unsigned long long)(unsigned)(8191 - val);
            skeys[c] = key;
            atomicAdd(&hist[HIDX((unsigned)(key >> 34))], 1u);
        }
    }
    __syncthreads();                                    // barrier 4

    if (ncv >= KK) {
        // ---- phase F: find bin B containing the 16th-largest key ----
        unsigned s8 = 0;
        #pragma unroll
        for (int j = 0; j < 8; ++j) s8 += hist[(j << 8) | t];   // bins 8t..8t+7
        sum256[t] = s8;
        __syncthreads();                                // barrier 5
        if (w == 0) {
            // stage 2: 64 chunks of 32 bins, scanned from top
            const int c = 63 - lane;
            unsigned c32 = 0;
            #pragma unroll
            for (int j = 0; j < 4; ++j) c32 += sum256[4 * c + j];
            unsigned p = c32;
            #pragma unroll
            for (int off = 1; off < 64; off <<= 1) {
                unsigned o = __shfl_up(p, off);
                if (lane >= off) p += o;
            }
            unsigned long long bal = __ballot(p >= (unsigned)KK);
            int l1 = (int)__ffsll((unsigned long long)bal) - 1;
            unsigned above1 = __shfl(p - c32, l1);
            int C = 63 - l1;
            // stage 3: 32 bins of chunk C, descending
            int b = 32 * C + 31 - lane;
            unsigned hb = (lane < 32) ? hist[HIDX(b)] : 0u;
            unsigned p2 = hb;
            #pragma unroll
            for (int off = 1; off < 64; off <<= 1) {
                unsigned o = __shfl_up(p2, off);
                if (lane >= off) p2 += o;
            }
            unsigned long long bal2 = __ballot(above1 + p2 >= (unsigned)KK);
            int l2 = (int)__ffsll((unsigned long long)bal2) - 1;
            if (lane == 0) B_sh = 32 * C + 31 - l2;
        }
        __syncthreads();                                // barrier 6 (hist now dead)
        const unsigned Bv = (unsigned)B_sh;

        // ---- phase G: append survivors (bin >= B); surv aliases dead hist ----
        for (int c = t; c < ncv; c += NT) {
            unsigned long long k = skeys[c];
            if ((unsigned)(k >> 34) >= Bv) { int s = atomicAdd(&nsurv, 1); surv[s] = k; }
        }
        __syncthreads();                                // barrier 7

        // ---- phase H: wave 0 sorts survivors exactly (u64 keys) ----
        if (w == 0) {
            const int S = nsurv;                        // >= 16 by construction
            unsigned long long kk = (lane < S) ? surv[lane] : 0ULL;
            sort64_desc(kk, lane);
            int processed = 64;
            while (processed < S) {                     // rare fallback: chunked resort
                if (lane >= 16) {
                    int idx = processed + (lane - 16);
                    kk = (idx < S) ? surv[idx] : 0ULL;
                }
                sort64_desc(kk, lane);
                processed += 48;
            }
            if (lane < KK)
                out[(size_t)i * KK + lane] = 8191 - (int)(kk & 0x1FFFULL);
        }
    } else {
        // rare: fewer than K uniques -> sorted uniques + pad with own samples
        if (t == 0) {
            int sorted_u[KK];
            int cnt2 = 0;
            for (int mw = 0; mw < NN / 32 && cnt2 < KK; ++mw) {
                unsigned b = mask[mw];
                while (b && cnt2 < KK) {
                    int bit = __ffs(b) - 1;
                    b &= b - 1;
                    sorted_u[cnt2++] = mw * 32 + bit;
                }
            }
            for (int j = 0; j < KK; ++j) {
                int uu;
                if (j < ncv) {
                    uu = sorted_u[j];
                } else {
                    int idx = j - ncv;
                    if (idx > KK - 1) idx = KK - 1;
                    uu = cs[(size_t)i * KK + idx];
                }
                out[(size_t)i * KK + j] = uu;
            }
        }
    }
}

extern "C" void kernel_launch(void* const* d_in, const int* in_sizes, int n_in,
                              void* d_out, int out_size, void* d_ws, size_t ws_size,
                              hipStream_t stream)
{
    const float* x   = (const float*)d_in[0];
    const float* adj = (const float*)d_in[1];
    const int*   cs  = (const int*)d_in[2];
    int* out = (int*)d_out;

    fused_kernel<<<NN, NT, 0, stream>>>(
        x, reinterpret_cast<const uvec4*>(adj), cs, out);
}